// Round 5
// baseline (414.360 us; speedup 1.0000x reference)
//
#include <hip/hip_runtime.h>

typedef __attribute__((ext_vector_type(8))) short short8;
typedef __attribute__((ext_vector_type(4))) short shrt4;
typedef __attribute__((ext_vector_type(8))) unsigned short ushort8;
typedef __attribute__((ext_vector_type(4))) unsigned short us4;
typedef __attribute__((ext_vector_type(4))) float f32x4;

#define S_LEN 2048
#define D_MODEL 1024
#define N_HEADS 16
#define HEAD_DIM 64

__device__ __forceinline__ unsigned short f2bf(float f) {
  union { float f; unsigned u; } x; x.f = f;
  unsigned r = x.u + 0x7FFFu + ((x.u >> 16) & 1u);
  return (unsigned short)(r >> 16);
}

// pack two f32 -> (bf16(a) | bf16(b)<<16), round-half-up, 3 VALU ops
__device__ __forceinline__ int pkbf(float a, float b) {
  union { float f; unsigned u; } x, y;
  x.f = a; y.f = b;
  return (int)__builtin_amdgcn_perm(y.u + 0x8000u, x.u + 0x8000u, 0x07060302u);
}

// ---------- fused fp32 -> bf16 convert for q,k,v ----------
__global__ __launch_bounds__(256) void cvt3_kernel(const float* __restrict__ a,
                                                   const float* __restrict__ b,
                                                   const float* __restrict__ c,
                                                   unsigned short* __restrict__ oa,
                                                   unsigned short* __restrict__ ob,
                                                   unsigned short* __restrict__ oc) {
  int bid = blockIdx.x;
  const float* in = (bid < 4096) ? a : (bid < 8192 ? b : c);
  unsigned short* out = (bid < 4096) ? oa : (bid < 8192 ? ob : oc);
  int i = (bid & 4095) * 256 + threadIdx.x;
  const f32x4* in4 = (const f32x4*)in;
  f32x4 x = in4[2 * i], y = in4[2 * i + 1];
  ushort8 o;
  o[0] = f2bf(x[0]); o[1] = f2bf(x[1]); o[2] = f2bf(x[2]); o[3] = f2bf(x[3]);
  o[4] = f2bf(y[0]); o[5] = f2bf(y[1]); o[6] = f2bf(y[2]); o[7] = f2bf(y[3]);
  ((ushort8*)out)[i] = o;
}

// ---------- all 4 weights: W [K][N] fp32 -> Wt [N][K] bf16, one dispatch ----------
__global__ __launch_bounds__(256) void transpose_w4(
    const float* __restrict__ Wq, const float* __restrict__ Wk,
    const float* __restrict__ Wv, const float* __restrict__ Wo,
    unsigned short* __restrict__ wqkvT, unsigned short* __restrict__ woT) {
  __shared__ float tile[64][65];
  const int z = blockIdx.z;
  const float* W = (z == 0) ? Wq : (z == 1) ? Wk : (z == 2) ? Wv : Wo;
  unsigned short* Wt = (z < 3) ? (wqkvT + (size_t)z * D_MODEL * D_MODEL) : woT;
  const int no = blockIdx.x * 64, ko = blockIdx.y * 64;
  const int tx = threadIdx.x & 63, ty = threadIdx.x >> 6;
  for (int r = ty; r < 64; r += 4)
    tile[r][tx] = W[(size_t)(ko + r) * D_MODEL + no + tx];
  __syncthreads();
  for (int r = ty; r < 64; r += 4)
    Wt[(size_t)(no + r) * D_MODEL + ko + tx] = f2bf(tile[tx][r]);
}

// ---------- 128x128x(BK=64) bf16 GEMM ----------
// MODE 0: fused QKV, N=3072; sel=n0>>10 picks A/bias/out.
//   sel 0,1 (Q,K): bf16 head-split [B,H,S,64] via LDS-transposed stores.
//   sel 2   (V):   bf16 TRANSPOSED [B,H,64,S] written directly.
// MODE 1: out proj, N=1024, fp32 row-major out via LDS-transposed dwordx4 stores.
template <int MODE>
__global__ __launch_bounds__(256) void proj_gemm(
    const unsigned short* __restrict__ A0,
    const unsigned short* __restrict__ A1,
    const unsigned short* __restrict__ A2,
    const unsigned short* __restrict__ Bt,
    const float* __restrict__ b0p, const float* __restrict__ b1p,
    const float* __restrict__ b2p,
    void* __restrict__ o0, void* __restrict__ o1, void* __restrict__ o2,
    float qscale) {
  __shared__ __align__(16) unsigned short sm[16384];  // As | Bs, reused by epilogue
  unsigned short* As = sm;
  unsigned short* Bs = sm + 8192;
  const int tid = threadIdx.x;
  const int wave = tid >> 6, lane = tid & 63;
  const int quad = lane >> 4, l16 = lane & 15;
  const int m0 = blockIdx.y * 128, n0 = blockIdx.x * 128;
  const int wm = (wave >> 1) * 64, wn = (wave & 1) * 64;

  const int sel = (MODE == 0) ? (n0 >> 10) : 0;
  const unsigned short* A = (MODE == 0) ? (sel == 0 ? A0 : sel == 1 ? A1 : A2) : A0;
  const float* bias = (MODE == 0) ? (sel == 0 ? b0p : sel == 1 ? b1p : b2p) : b0p;
  const float scale = (MODE == 0 && sel == 0) ? qscale : 1.0f;
  const int nb = (MODE == 0) ? (n0 & 1023) : n0;

  f32x4 acc[4][4] = {};

  int grow[4], gcol[4];
  for (int i = 0; i < 4; ++i) {
    int cid = (wave * 4 + i) * 64 + lane;
    int r = cid >> 3;
    grow[i] = r;
    gcol[i] = ((cid & 7) ^ (r & 7)) * 8;
  }

  for (int k0 = 0; k0 < D_MODEL; k0 += 64) {
#pragma unroll
    for (int i = 0; i < 4; ++i) {
      const unsigned short* g = A + (size_t)(m0 + grow[i]) * D_MODEL + k0 + gcol[i];
      __builtin_amdgcn_global_load_lds((const __attribute__((address_space(1))) void*)g,
          (__attribute__((address_space(3))) void*)(As + (wave * 4 + i) * 512), 16, 0, 0);
    }
#pragma unroll
    for (int i = 0; i < 4; ++i) {
      const unsigned short* g = Bt + (size_t)(n0 + grow[i]) * D_MODEL + k0 + gcol[i];
      __builtin_amdgcn_global_load_lds((const __attribute__((address_space(1))) void*)g,
          (__attribute__((address_space(3))) void*)(Bs + (wave * 4 + i) * 512), 16, 0, 0);
    }
    __syncthreads();
#pragma unroll
    for (int t = 0; t < 2; ++t) {
      short8 af[4], bf[4];
#pragma unroll
      for (int i = 0; i < 4; ++i) {
        int r = wm + i * 16 + l16;
        af[i] = *(const short8*)(As + r * 64 + (((t * 4 + quad) ^ (r & 7)) << 3));
      }
#pragma unroll
      for (int j = 0; j < 4; ++j) {
        int r = wn + j * 16 + l16;
        bf[j] = *(const short8*)(Bs + r * 64 + (((t * 4 + quad) ^ (r & 7)) << 3));
      }
#pragma unroll
      for (int i = 0; i < 4; ++i)
#pragma unroll
        for (int j = 0; j < 4; ++j)
          acc[i][j] = __builtin_amdgcn_mfma_f32_16x16x32_bf16(af[i], bf[j], acc[i][j], 0, 0, 0);
    }
    __syncthreads();
  }

  float bv4[4];
#pragma unroll
  for (int j = 0; j < 4; ++j) bv4[j] = bias[nb + wn + j * 16 + l16];

  if (MODE == 0) {
    if (sel < 2) {
      unsigned short* T = As + wave * 1152;
      unsigned short* out = (unsigned short*)(sel == 0 ? o0 : o1);
      const int h = (nb + wn) >> 6;
#pragma unroll
      for (int i = 0; i < 4; ++i) {
#pragma unroll
        for (int j = 0; j < 4; ++j)
#pragma unroll
          for (int r = 0; r < 4; ++r)
            T[(quad * 4 + r) * 72 + j * 16 + l16] = f2bf((acc[i][j][r] + bv4[j]) * scale);
        int m = m0 + wm + i * 16 + l16;
        int b = m >> 11, s = m & 2047;
#pragma unroll
        for (int t = 0; t < 2; ++t) {
          short8 row = *(const short8*)(T + l16 * 72 + t * 32 + quad * 8);
          *(short8*)(out + (((size_t)(b * N_HEADS + h) * S_LEN + s) << 6) + t * 32 + quad * 8) = row;
        }
      }
    } else {
      unsigned short* vt = (unsigned short*)o2;
#pragma unroll
      for (int i = 0; i < 4; ++i) {
        int m = m0 + wm + i * 16 + quad * 4;
        int b = m >> 11, s = m & 2047;
#pragma unroll
        for (int j = 0; j < 4; ++j) {
          int n = nb + wn + j * 16 + l16;
          int h = n >> 6, d = n & 63;
          us4 pv;
#pragma unroll
          for (int r = 0; r < 4; ++r) pv[r] = f2bf(acc[i][j][r] + bv4[j]);
          *(us4*)(vt + (((size_t)(b * N_HEADS + h) * 64 + d) << 11) + s) = pv;
        }
      }
    }
  } else {
    float* Tf = (float*)sm + wave * 1088;
    float* out = (float*)o0;
#pragma unroll
    for (int i = 0; i < 4; ++i) {
#pragma unroll
      for (int j = 0; j < 4; ++j)
#pragma unroll
        for (int r = 0; r < 4; ++r)
          Tf[(quad * 4 + r) * 68 + j * 16 + l16] = acc[i][j][r] + bv4[j];
      int m = m0 + wm + i * 16 + l16;
#pragma unroll
      for (int t = 0; t < 4; ++t) {
        f32x4 row = *(const f32x4*)(Tf + l16 * 68 + t * 16 + quad * 4);
        *(f32x4*)(out + (size_t)m * D_MODEL + nb + wn + t * 16 + quad * 4) = row;
      }
    }
  }
}

// ---------- causal flash attention: key-split waves, K in registers, V triple-buffered ----------
// Q pre-scaled by 0.125*log2(e). Wave w owns keys w*16..+15 per tile; K for those rows
// goes global->VGPR (prefetched 1 tile ahead, never touches LDS). V (cross-wave) is
// triple-buffered in LDS with stage issued AFTER the top-of-loop barrier, so the
// barrier's vmcnt(0) drain only waits on loads issued a full iteration earlier.
__global__ __launch_bounds__(256) void flash_attn(
    const unsigned short* __restrict__ Qh,  // [B,H,S,64] bf16 (scaled)
    const unsigned short* __restrict__ Kh,  // [B,H,S,64] bf16
    const unsigned short* __restrict__ Vt,  // [B,H,64,S] bf16
    unsigned short* __restrict__ ctx) {     // [B,S,1024] bf16
  __shared__ __align__(16) unsigned short smem[12288];  // 24 KB: V x3 (4096 shorts each)
  const int tid = threadIdx.x;
  const int wave = tid >> 6, lane = tid & 63;
  const int quad = lane >> 4, l16 = lane & 15;
  const int l7 = l16 & 7;
  const int qi = (blockIdx.x + blockIdx.y) & 31;  // CU-balanced work mapping
  const int bh = blockIdx.y;
  const int q0 = qi * 64;
  const size_t hb = (size_t)bh * (S_LEN * HEAD_DIM);
  const int srow = lane >> 3;
  const int schunk = ((lane & 7) ^ srow) * 8;

  // stage V d-rows for one tile into buffer buf (each wave stages its 16 d-rows)
  auto stageV = [&](int kt, int buf) {
    unsigned short* Vb = smem + buf * 4096;
#pragma unroll
    for (int c = 0; c < 2; ++c) {
      int row = wave * 16 + c * 8 + srow;
      const unsigned short* gv = Vt + hb + (size_t)row * S_LEN + kt * 64 + schunk;
      __builtin_amdgcn_global_load_lds((const __attribute__((address_space(1))) void*)gv,
          (__attribute__((address_space(3))) void*)(Vb + (wave * 16 + c * 8) * 64), 16, 0, 0);
    }
  };
  // wave-private K rows -> registers (A-frag layout directly)
  auto loadK = [&](int kt, short8* kf) {
    const unsigned short* base = Kh + hb + (size_t)(kt * 64 + wave * 16 + l16) * 64;
    kf[0] = *(const short8*)(base + quad * 8);
    kf[1] = *(const short8*)(base + 32 + quad * 8);
  };

  stageV(0, 0);
  if (qi >= 1) stageV(1, 1);
  short8 kcur[2], knxt[2];
  loadK(0, kcur);

  // Q B-fragments, all 64 queries, register-resident
  short8 qf[8];
#pragma unroll
  for (int ntq = 0; ntq < 4; ++ntq)
#pragma unroll
    for (int t = 0; t < 2; ++t)
      qf[ntq * 2 + t] = *(const short8*)(Qh + hb + (size_t)(q0 + ntq * 16 + l16) * 64 + t * 32 + quad * 8);

  f32x4 o[4][4] = {};  // o[ntd][ntq]: rows d=ntd*16+quad*4+r, cols q=ntq*16+l16
  float rsum[4] = {0.f, 0.f, 0.f, 0.f};

  for (int kt = 0; kt <= qi; ++kt) {
    __syncthreads();  // drains loads issued >=1 iteration ago; tile kt data now ready
    if (kt + 2 <= qi) stageV(kt + 2, (kt + 2) % 3);  // buffer free: last read at kt-1
    if (kt + 1 <= qi) loadK(kt + 1, knxt);
    const unsigned short* Vb = smem + (kt % 3) * 4096;

    // S^T = K_w Q^T
    f32x4 sc[4];
#pragma unroll
    for (int ntq = 0; ntq < 4; ++ntq) {
      f32x4 z = {};
      z = __builtin_amdgcn_mfma_f32_16x16x32_bf16(kcur[0], qf[ntq * 2], z, 0, 0, 0);
      sc[ntq] = __builtin_amdgcn_mfma_f32_16x16x32_bf16(kcur[1], qf[ntq * 2 + 1], z, 0, 0, 0);
    }
    if (kt == qi) {  // diagonal: mask key > query
      int keyb = wave * 16 + quad * 4;
#pragma unroll
      for (int ntq = 0; ntq < 4; ++ntq)
#pragma unroll
        for (int r = 0; r < 4; ++r)
          if (keyb + r > ntq * 16 + l16) sc[ntq][r] = -1e30f;
    }

    // fixed-base softmax numerator + direct B-frag pack (no shuffles)
    union { int i[4]; short8 v; } pf[4];
#pragma unroll
    for (int ntq = 0; ntq < 4; ++ntq) {
      float p0 = exp2f(sc[ntq][0]);
      float p1 = exp2f(sc[ntq][1]);
      float p2 = exp2f(sc[ntq][2]);
      float p3 = exp2f(sc[ntq][3]);
      rsum[ntq] += (p0 + p1) + (p2 + p3);
      pf[ntq].i[0] = pkbf(p0, p1);
      pf[ntq].i[1] = pkbf(p2, p3);
      pf[ntq].i[2] = 0;
      pf[ntq].i[3] = 0;
    }

    // O += V_w^T P_w^T : A = V d-rows, wave's 16 key cols; upper k-half zeroed
    const int voff = (((wave * 2 + (quad >> 1)) ^ l7) << 3) + ((quad & 1) << 2);
#pragma unroll
    for (int ntd = 0; ntd < 4; ++ntd) {
      shrt4 v4 = *(const shrt4*)(Vb + (ntd * 16 + l16) * 64 + voff);
      short8 av = {v4[0], v4[1], v4[2], v4[3], 0, 0, 0, 0};
#pragma unroll
      for (int ntq = 0; ntq < 4; ++ntq)
        o[ntd][ntq] = __builtin_amdgcn_mfma_f32_16x16x32_bf16(av, pf[ntq].v, o[ntd][ntq], 0, 0, 0);
    }
    kcur[0] = knxt[0];
    kcur[1] = knxt[1];
  }

  // reduce rsum over quads
#pragma unroll
  for (int ntq = 0; ntq < 4; ++ntq) {
    rsum[ntq] += __shfl_xor(rsum[ntq], 16, 64);
    rsum[ntq] += __shfl_xor(rsum[ntq], 32, 64);
  }

  // 3-round strip exchange: wave w accumulates all partials for queries w*16..+15
  float* SP = (float*)smem;          // 4 strips of [16 q][68 d] f32
  float* RS = (float*)smem + 4352;   // 4 strips of [16] f32
  f32x4 racc[4];
  float rs_acc = 0.f;
#pragma unroll
  for (int ntq = 0; ntq < 4; ++ntq)
    if (ntq == wave) {
#pragma unroll
      for (int ntd = 0; ntd < 4; ++ntd) racc[ntd] = o[ntd][ntq];
      rs_acc = rsum[ntq];
    }
  for (int t = 1; t < 4; ++t) {
    __syncthreads();
#pragma unroll
    for (int ntq = 0; ntq < 4; ++ntq)
      if (((wave + t) & 3) == ntq) {
#pragma unroll
        for (int ntd = 0; ntd < 4; ++ntd)
          *(f32x4*)(SP + ntq * 1088 + l16 * 68 + ntd * 16 + quad * 4) = o[ntd][ntq];
        if (quad == 0) RS[ntq * 16 + l16] = rsum[ntq];
      }
    __syncthreads();
#pragma unroll
    for (int ntd = 0; ntd < 4; ++ntd)
      racc[ntd] += *(const f32x4*)(SP + wave * 1088 + l16 * 68 + ntd * 16 + quad * 4);
    rs_acc += RS[wave * 16 + l16];
  }

  const float invl = 1.0f / rs_acc;
  const int b = bh >> 4, h = bh & 15;
  const int q = q0 + wave * 16 + l16;
#pragma unroll
  for (int ntd = 0; ntd < 4; ++ntd) {
    us4 pv;
#pragma unroll
    for (int r = 0; r < 4; ++r) pv[r] = f2bf(racc[ntd][r] * invl);
    *(us4*)(ctx + (((size_t)(b * S_LEN + q)) << 10) + h * 64 + ntd * 16 + quad * 4) = pv;
  }
}

// ---------- launch ----------
extern "C" void kernel_launch(void* const* d_in, const int* in_sizes, int n_in,
                              void* d_out, int out_size, void* d_ws, size_t ws_size,
                              hipStream_t stream) {
  (void)in_sizes; (void)n_in; (void)out_size;
  const float* q  = (const float*)d_in[0];
  const float* k  = (const float*)d_in[1];
  const float* v  = (const float*)d_in[2];
  const float* Wq = (const float*)d_in[4];
  const float* bq = (const float*)d_in[5];
  const float* Wk = (const float*)d_in[6];
  const float* bk = (const float*)d_in[7];
  const float* Wv = (const float*)d_in[8];
  const float* bv = (const float*)d_in[9];
  const float* Wo = (const float*)d_in[10];
  const float* bo = (const float*)d_in[11];
  float* out = (float*)d_out;

  if (ws_size < 109051904u) return;
  char* ws = (char*)d_ws;
  unsigned short* xq    = (unsigned short*)(ws);
  unsigned short* xk    = (unsigned short*)(ws + 16777216);
  unsigned short* xv    = (unsigned short*)(ws + 33554432);
  unsigned short* wqkvT = (unsigned short*)(ws + 50331648);  // [3072][1024] = 6 MB
  unsigned short* woT   = (unsigned short*)(ws + 56623104);
  unsigned short* qh    = (unsigned short*)(ws + 58720256);
  unsigned short* kh    = qh + 8388608;
  unsigned short* vt    = kh + 8388608;  // [B,H,64,S] written directly by proj<0>
  unsigned short* ctx   = xq;            // xq dead after QKV projection

  cvt3_kernel<<<12288, 256, 0, stream>>>(q, k, v, xq, xk, xv);
  transpose_w4<<<dim3(16, 16, 4), 256, 0, stream>>>(Wq, Wk, Wv, Wo, wqkvT, woT);
  // fused QKV projection; Q scale folds 1/sqrt(64) and log2(e)
  proj_gemm<0><<<dim3(24, 64), 256, 0, stream>>>(xq, xk, xv, wqkvT, bq, bk, bv,
                                                 qh, kh, vt, 0.125f * 1.44269504088896f);
  flash_attn<<<dim3(32, 64), 256, 0, stream>>>(qh, kh, vt, ctx);
  proj_gemm<1><<<dim3(8, 64), 256, 0, stream>>>(ctx, ctx, ctx, woT, bo, bo, bo,
                                                out, out, out, 1.0f);
}

// Round 6
// 385.638 us; speedup vs baseline: 1.0745x; 1.0745x over previous
//
#include <hip/hip_runtime.h>

typedef __attribute__((ext_vector_type(8))) short short8;
typedef __attribute__((ext_vector_type(8))) unsigned short ushort8;
typedef __attribute__((ext_vector_type(4))) unsigned short us4;
typedef __attribute__((ext_vector_type(4))) float f32x4;

#define S_LEN 2048
#define D_MODEL 1024
#define N_HEADS 16
#define HEAD_DIM 64

__device__ __forceinline__ unsigned short f2bf(float f) {
  union { float f; unsigned u; } x; x.f = f;
  unsigned r = x.u + 0x7FFFu + ((x.u >> 16) & 1u);
  return (unsigned short)(r >> 16);
}

// pack two f32 -> (bf16(a) | bf16(b)<<16), round-half-up, 3 VALU ops
__device__ __forceinline__ int pkbf(float a, float b) {
  union { float f; unsigned u; } x, y;
  x.f = a; y.f = b;
  return (int)__builtin_amdgcn_perm(y.u + 0x8000u, x.u + 0x8000u, 0x07060302u);
}

// ---------- fused fp32 -> bf16 convert for q,k,v ----------
__global__ __launch_bounds__(256) void cvt3_kernel(const float* __restrict__ a,
                                                   const float* __restrict__ b,
                                                   const float* __restrict__ c,
                                                   unsigned short* __restrict__ oa,
                                                   unsigned short* __restrict__ ob,
                                                   unsigned short* __restrict__ oc) {
  int bid = blockIdx.x;
  const float* in = (bid < 4096) ? a : (bid < 8192 ? b : c);
  unsigned short* out = (bid < 4096) ? oa : (bid < 8192 ? ob : oc);
  int i = (bid & 4095) * 256 + threadIdx.x;
  const f32x4* in4 = (const f32x4*)in;
  f32x4 x = in4[2 * i], y = in4[2 * i + 1];
  ushort8 o;
  o[0] = f2bf(x[0]); o[1] = f2bf(x[1]); o[2] = f2bf(x[2]); o[3] = f2bf(x[3]);
  o[4] = f2bf(y[0]); o[5] = f2bf(y[1]); o[6] = f2bf(y[2]); o[7] = f2bf(y[3]);
  ((ushort8*)out)[i] = o;
}

// ---------- all 4 weights: W [K][N] fp32 -> Wt [N][K] bf16, one dispatch ----------
__global__ __launch_bounds__(256) void transpose_w4(
    const float* __restrict__ Wq, const float* __restrict__ Wk,
    const float* __restrict__ Wv, const float* __restrict__ Wo,
    unsigned short* __restrict__ wqkvT, unsigned short* __restrict__ woT) {
  __shared__ float tile[64][65];
  const int z = blockIdx.z;
  const float* W = (z == 0) ? Wq : (z == 1) ? Wk : (z == 2) ? Wv : Wo;
  unsigned short* Wt = (z < 3) ? (wqkvT + (size_t)z * D_MODEL * D_MODEL) : woT;
  const int no = blockIdx.x * 64, ko = blockIdx.y * 64;
  const int tx = threadIdx.x & 63, ty = threadIdx.x >> 6;
  for (int r = ty; r < 64; r += 4)
    tile[r][tx] = W[(size_t)(ko + r) * D_MODEL + no + tx];
  __syncthreads();
  for (int r = ty; r < 64; r += 4)
    Wt[(size_t)(no + r) * D_MODEL + ko + tx] = f2bf(tile[tx][r]);
}

// ---------- 128x128x(BK=64) bf16 GEMM ----------
// MODE 0: fused QKV, N=3072; sel=n0>>10 picks A/bias/out.
//   sel 0,1 (Q,K): bf16 head-split [B,H,S,64] via LDS-transposed stores.
//   sel 2   (V):   bf16 TRANSPOSED [B,H,64,S] written directly.
// MODE 1: out proj, N=1024, fp32 row-major out via LDS-transposed dwordx4 stores.
template <int MODE>
__global__ __launch_bounds__(256) void proj_gemm(
    const unsigned short* __restrict__ A0,
    const unsigned short* __restrict__ A1,
    const unsigned short* __restrict__ A2,
    const unsigned short* __restrict__ Bt,
    const float* __restrict__ b0p, const float* __restrict__ b1p,
    const float* __restrict__ b2p,
    void* __restrict__ o0, void* __restrict__ o1, void* __restrict__ o2,
    float qscale) {
  __shared__ __align__(16) unsigned short sm[16384];  // As | Bs, reused by epilogue
  unsigned short* As = sm;
  unsigned short* Bs = sm + 8192;
  const int tid = threadIdx.x;
  const int wave = tid >> 6, lane = tid & 63;
  const int quad = lane >> 4, l16 = lane & 15;
  const int m0 = blockIdx.y * 128, n0 = blockIdx.x * 128;
  const int wm = (wave >> 1) * 64, wn = (wave & 1) * 64;

  const int sel = (MODE == 0) ? (n0 >> 10) : 0;
  const unsigned short* A = (MODE == 0) ? (sel == 0 ? A0 : sel == 1 ? A1 : A2) : A0;
  const float* bias = (MODE == 0) ? (sel == 0 ? b0p : sel == 1 ? b1p : b2p) : b0p;
  const float scale = (MODE == 0 && sel == 0) ? qscale : 1.0f;
  const int nb = (MODE == 0) ? (n0 & 1023) : n0;

  f32x4 acc[4][4] = {};

  int grow[4], gcol[4];
  for (int i = 0; i < 4; ++i) {
    int cid = (wave * 4 + i) * 64 + lane;
    int r = cid >> 3;
    grow[i] = r;
    gcol[i] = ((cid & 7) ^ (r & 7)) * 8;
  }

  for (int k0 = 0; k0 < D_MODEL; k0 += 64) {
#pragma unroll
    for (int i = 0; i < 4; ++i) {
      const unsigned short* g = A + (size_t)(m0 + grow[i]) * D_MODEL + k0 + gcol[i];
      __builtin_amdgcn_global_load_lds((const __attribute__((address_space(1))) void*)g,
          (__attribute__((address_space(3))) void*)(As + (wave * 4 + i) * 512), 16, 0, 0);
    }
#pragma unroll
    for (int i = 0; i < 4; ++i) {
      const unsigned short* g = Bt + (size_t)(n0 + grow[i]) * D_MODEL + k0 + gcol[i];
      __builtin_amdgcn_global_load_lds((const __attribute__((address_space(1))) void*)g,
          (__attribute__((address_space(3))) void*)(Bs + (wave * 4 + i) * 512), 16, 0, 0);
    }
    __syncthreads();
#pragma unroll
    for (int t = 0; t < 2; ++t) {
      short8 af[4], bf[4];
#pragma unroll
      for (int i = 0; i < 4; ++i) {
        int r = wm + i * 16 + l16;
        af[i] = *(const short8*)(As + r * 64 + (((t * 4 + quad) ^ (r & 7)) << 3));
      }
#pragma unroll
      for (int j = 0; j < 4; ++j) {
        int r = wn + j * 16 + l16;
        bf[j] = *(const short8*)(Bs + r * 64 + (((t * 4 + quad) ^ (r & 7)) << 3));
      }
#pragma unroll
      for (int i = 0; i < 4; ++i)
#pragma unroll
        for (int j = 0; j < 4; ++j)
          acc[i][j] = __builtin_amdgcn_mfma_f32_16x16x32_bf16(af[i], bf[j], acc[i][j], 0, 0, 0);
    }
    __syncthreads();
  }

  float bv4[4];
#pragma unroll
  for (int j = 0; j < 4; ++j) bv4[j] = bias[nb + wn + j * 16 + l16];

  if (MODE == 0) {
    if (sel < 2) {
      unsigned short* T = As + wave * 1152;
      unsigned short* out = (unsigned short*)(sel == 0 ? o0 : o1);
      const int h = (nb + wn) >> 6;
#pragma unroll
      for (int i = 0; i < 4; ++i) {
#pragma unroll
        for (int j = 0; j < 4; ++j)
#pragma unroll
          for (int r = 0; r < 4; ++r)
            T[(quad * 4 + r) * 72 + j * 16 + l16] = f2bf((acc[i][j][r] + bv4[j]) * scale);
        int m = m0 + wm + i * 16 + l16;
        int b = m >> 11, s = m & 2047;
#pragma unroll
        for (int t = 0; t < 2; ++t) {
          short8 row = *(const short8*)(T + l16 * 72 + t * 32 + quad * 8);
          *(short8*)(out + (((size_t)(b * N_HEADS + h) * S_LEN + s) << 6) + t * 32 + quad * 8) = row;
        }
      }
    } else {
      unsigned short* vt = (unsigned short*)o2;
#pragma unroll
      for (int i = 0; i < 4; ++i) {
        int m = m0 + wm + i * 16 + quad * 4;
        int b = m >> 11, s = m & 2047;
#pragma unroll
        for (int j = 0; j < 4; ++j) {
          int n = nb + wn + j * 16 + l16;
          int h = n >> 6, d = n & 63;
          us4 pv;
#pragma unroll
          for (int r = 0; r < 4; ++r) pv[r] = f2bf(acc[i][j][r] + bv4[j]);
          *(us4*)(vt + (((size_t)(b * N_HEADS + h) * 64 + d) << 11) + s) = pv;
        }
      }
    }
  } else {
    float* Tf = (float*)sm + wave * 1088;
    float* out = (float*)o0;
#pragma unroll
    for (int i = 0; i < 4; ++i) {
#pragma unroll
      for (int j = 0; j < 4; ++j)
#pragma unroll
        for (int r = 0; r < 4; ++r)
          Tf[(quad * 4 + r) * 68 + j * 16 + l16] = acc[i][j][r] + bv4[j];
      int m = m0 + wm + i * 16 + l16;
#pragma unroll
      for (int t = 0; t < 4; ++t) {
        f32x4 row = *(const f32x4*)(Tf + l16 * 68 + t * 16 + quad * 4);
        *(f32x4*)(out + (size_t)m * D_MODEL + nb + wn + t * 16 + quad * 4) = row;
      }
    }
  }
}

// ---------- causal flash attention: R3 q-split structure + 128-q blocks + K/V dbuf ----------
// Q pre-scaled by 0.125*log2(e). Block owns 128 queries (qi*128..); wave owns 32
// (2 strips of 16). K/V staged per 64-key tile, double-buffered; stage(kt+1) is
// issued AFTER the top-of-loop barrier so the barrier's vmcnt(0) drain only waits
// on loads issued a full compute-phase earlier. K/V frag reads shared across strips.
__global__ __launch_bounds__(256, 4) void flash_attn(
    const unsigned short* __restrict__ Qh,  // [B,H,S,64] bf16 (scaled)
    const unsigned short* __restrict__ Kh,  // [B,H,S,64] bf16
    const unsigned short* __restrict__ Vt,  // [B,H,64,S] bf16
    unsigned short* __restrict__ ctx) {     // [B,S,1024] bf16
  __shared__ __align__(16) unsigned short smem[16384];  // 32 KB: 2 x (K 8KB | V 8KB)
  const int tid = threadIdx.x;
  const int wave = tid >> 6, lane = tid & 63;
  const int quad = lane >> 4, l16 = lane & 15;
  const int l7 = l16 & 7;
  const int bh = blockIdx.y;
  // balance: t16 steps by 1 per +256 blocks; fold -> {0,15,1,14,..} so the 4
  // co-resident blocks per CU sum to ~constant causal work
  const int t16 = (blockIdx.x + blockIdx.y + (blockIdx.y >> 4)) & 15;
  const int qi = (t16 & 1) ? (15 - (t16 >> 1)) : (t16 >> 1);
  const int q0 = qi * 128;
  const int nk = 2 * qi + 2;
  const size_t hb = (size_t)bh * (S_LEN * HEAD_DIM);
  const int srow = lane >> 3;
  const int schunk = ((lane & 7) ^ srow) * 8;

  auto stage = [&](int kt, int buf) {
    unsigned short* Kb = smem + buf * 8192;
    unsigned short* Vb = smem + buf * 8192 + 4096;
#pragma unroll
    for (int c = 0; c < 2; ++c) {
      int row = wave * 16 + c * 8 + srow;
      const unsigned short* gk = Kh + hb + (size_t)(kt * 64 + row) * 64 + schunk;
      __builtin_amdgcn_global_load_lds((const __attribute__((address_space(1))) void*)gk,
          (__attribute__((address_space(3))) void*)(Kb + (wave * 16 + c * 8) * 64), 16, 0, 0);
      const unsigned short* gv = Vt + hb + (size_t)row * S_LEN + kt * 64 + schunk;
      __builtin_amdgcn_global_load_lds((const __attribute__((address_space(1))) void*)gv,
          (__attribute__((address_space(3))) void*)(Vb + (wave * 16 + c * 8) * 64), 16, 0, 0);
    }
  };

  stage(0, 0);

  // Q B-fragments for both strips, register-resident (coalesced global reads)
  short8 qf[2][2];
#pragma unroll
  for (int s = 0; s < 2; ++s)
#pragma unroll
    for (int t = 0; t < 2; ++t)
      qf[s][t] = *(const short8*)(Qh + hb +
          (size_t)(q0 + wave * 32 + s * 16 + l16) * 64 + t * 32 + quad * 8);

  f32x4 o[4][2] = {};  // o[ntd][s]: d=ntd*16+quad*4+r, query=strip s col l16
  float rsum[2] = {0.f, 0.f};

  for (int kt = 0; kt < nk; ++kt) {
    __syncthreads();  // drains stage issued last iteration; buf[kt&1] now ready
    if (kt + 1 < nk) stage(kt + 1, (kt + 1) & 1);
    const unsigned short* Kb = smem + (kt & 1) * 8192;
    const unsigned short* Vb = Kb + 4096;

    // wave-uniform skip: all keys of this tile beyond wave's max query
    if (kt * 64 > q0 + wave * 32 + 31) continue;

    // S^T = K Q^T per strip (K A-frags shared across strips)
    f32x4 sc[2][4];
#pragma unroll
    for (int nt = 0; nt < 4; ++nt) {
      short8 k0 = *(const short8*)(Kb + (nt * 16 + l16) * 64 + ((quad ^ l7) << 3));
      short8 k1 = *(const short8*)(Kb + (nt * 16 + l16) * 64 + (((4 + quad) ^ l7) << 3));
#pragma unroll
      for (int s = 0; s < 2; ++s) {
        f32x4 z = {};
        z = __builtin_amdgcn_mfma_f32_16x16x32_bf16(k0, qf[s][0], z, 0, 0, 0);
        sc[s][nt] = __builtin_amdgcn_mfma_f32_16x16x32_bf16(k1, qf[s][1], z, 0, 0, 0);
      }
    }
    if (kt >= 2 * qi) {  // only the last two tiles can touch the diagonal
#pragma unroll
      for (int s = 0; s < 2; ++s) {
        int qg = q0 + wave * 32 + s * 16 + l16;
#pragma unroll
        for (int nt = 0; nt < 4; ++nt) {
          int kg = kt * 64 + nt * 16 + quad * 4;
#pragma unroll
          for (int r = 0; r < 4; ++r)
            if (kg + r > qg) sc[s][nt][r] = -1e30f;
        }
      }
    }

    // fixed-base softmax numerator + P^T B-frag transform (R3-verified shuffle)
    union { int i[4]; short8 v; } pf[2][2];
#pragma unroll
    for (int s = 0; s < 2; ++s) {
      int pk[4][2];
#pragma unroll
      for (int nt = 0; nt < 4; ++nt) {
        float p0 = exp2f(sc[s][nt][0]);
        float p1 = exp2f(sc[s][nt][1]);
        float p2 = exp2f(sc[s][nt][2]);
        float p3 = exp2f(sc[s][nt][3]);
        rsum[s] += (p0 + p1) + (p2 + p3);
        pk[nt][0] = pkbf(p0, p1);
        pk[nt][1] = pkbf(p2, p3);
      }
      const int s0 = ((quad & 1) << 5) + l16;
      const int s1 = s0 + 16;
      const bool hi = (quad & 2) != 0;
#pragma unroll
      for (int t = 0; t < 2; ++t) {
        int a0 = __shfl(pk[t * 2][0], s0, 64), b0 = __shfl(pk[t * 2 + 1][0], s0, 64);
        int a1 = __shfl(pk[t * 2][1], s0, 64), b1 = __shfl(pk[t * 2 + 1][1], s0, 64);
        int a2 = __shfl(pk[t * 2][0], s1, 64), b2 = __shfl(pk[t * 2 + 1][0], s1, 64);
        int a3 = __shfl(pk[t * 2][1], s1, 64), b3 = __shfl(pk[t * 2 + 1][1], s1, 64);
        pf[s][t].i[0] = hi ? b0 : a0;
        pf[s][t].i[1] = hi ? b1 : a1;
        pf[s][t].i[2] = hi ? b2 : a2;
        pf[s][t].i[3] = hi ? b3 : a3;
      }
    }

    // O^T += V^T P^T (V A-frags shared across strips)
#pragma unroll
    for (int ntd = 0; ntd < 4; ++ntd) {
      short8 v0 = *(const short8*)(Vb + (ntd * 16 + l16) * 64 + ((quad ^ l7) << 3));
      short8 v1 = *(const short8*)(Vb + (ntd * 16 + l16) * 64 + (((4 + quad) ^ l7) << 3));
#pragma unroll
      for (int s = 0; s < 2; ++s) {
        o[ntd][s] = __builtin_amdgcn_mfma_f32_16x16x32_bf16(v0, pf[s][0].v, o[ntd][s], 0, 0, 0);
        o[ntd][s] = __builtin_amdgcn_mfma_f32_16x16x32_bf16(v1, pf[s][1].v, o[ntd][s], 0, 0, 0);
      }
    }
  }

  // l reduction over quads (linear softmax base -> once at the end)
#pragma unroll
  for (int s = 0; s < 2; ++s) {
    rsum[s] += __shfl_xor(rsum[s], 16, 64);
    rsum[s] += __shfl_xor(rsum[s], 32, 64);
  }

  // epilogue: O^T -> LDS transpose -> coalesced stores
  __syncthreads();
  unsigned short* Os = smem;  // [128 q][72]
#pragma unroll
  for (int s = 0; s < 2; ++s) {
    float invl = 1.0f / rsum[s];
#pragma unroll
    for (int ntd = 0; ntd < 4; ++ntd) {
      us4 pk4;
#pragma unroll
      for (int r = 0; r < 4; ++r) pk4[r] = f2bf(o[ntd][s][r] * invl);
      *(us4*)(Os + (wave * 32 + s * 16 + l16) * 72 + ntd * 16 + quad * 4) = pk4;
    }
  }
  __syncthreads();
  const int b = bh >> 4, h = bh & 15;
#pragma unroll
  for (int it = 0; it < 4; ++it) {
    int e = it * 256 + tid;
    int row = e >> 3, c = (e & 7) * 8;
    short8 vrow = *(const short8*)(Os + row * 72 + c);
    *(short8*)(ctx + (size_t)(b * S_LEN + q0 + row) * D_MODEL + h * HEAD_DIM + c) = vrow;
  }
}

// ---------- launch ----------
extern "C" void kernel_launch(void* const* d_in, const int* in_sizes, int n_in,
                              void* d_out, int out_size, void* d_ws, size_t ws_size,
                              hipStream_t stream) {
  (void)in_sizes; (void)n_in; (void)out_size;
  const float* q  = (const float*)d_in[0];
  const float* k  = (const float*)d_in[1];
  const float* v  = (const float*)d_in[2];
  const float* Wq = (const float*)d_in[4];
  const float* bq = (const float*)d_in[5];
  const float* Wk = (const float*)d_in[6];
  const float* bk = (const float*)d_in[7];
  const float* Wv = (const float*)d_in[8];
  const float* bv = (const float*)d_in[9];
  const float* Wo = (const float*)d_in[10];
  const float* bo = (const float*)d_in[11];
  float* out = (float*)d_out;

  if (ws_size < 109051904u) return;
  char* ws = (char*)d_ws;
  unsigned short* xq    = (unsigned short*)(ws);
  unsigned short* xk    = (unsigned short*)(ws + 16777216);
  unsigned short* xv    = (unsigned short*)(ws + 33554432);
  unsigned short* wqkvT = (unsigned short*)(ws + 50331648);  // [3072][1024] = 6 MB
  unsigned short* woT   = (unsigned short*)(ws + 56623104);
  unsigned short* qh    = (unsigned short*)(ws + 58720256);
  unsigned short* kh    = qh + 8388608;
  unsigned short* vt    = kh + 8388608;  // [B,H,64,S] written directly by proj<0>
  unsigned short* ctx   = xq;            // xq dead after QKV projection

  cvt3_kernel<<<12288, 256, 0, stream>>>(q, k, v, xq, xk, xv);
  transpose_w4<<<dim3(16, 16, 4), 256, 0, stream>>>(Wq, Wk, Wv, Wo, wqkvT, woT);
  // fused QKV projection; Q scale folds 1/sqrt(64) and log2(e)
  proj_gemm<0><<<dim3(24, 64), 256, 0, stream>>>(xq, xk, xv, wqkvT, bq, bk, bv,
                                                 qh, kh, vt, 0.125f * 1.44269504088896f);
  flash_attn<<<dim3(16, 64), 256, 0, stream>>>(qh, kh, vt, ctx);
  proj_gemm<1><<<dim3(8, 64), 256, 0, stream>>>(ctx, ctx, ctx, woT, bo, bo, bo,
                                                out, out, out, 1.0f);
}